// Round 2
// baseline (1739.725 us; speedup 1.0000x reference)
//
#include <hip/hip_runtime.h>
#include <math.h>

#define NN 100000
#define NE 1000000
#define D 64
#define L 3
#define RVQ 3
#define CODES 16
#define BN_EPS 1e-5f
#define COMMIT_W 0.25f

#define GRID_A 2048   // blocks for layer kernels (fixed: partials buffer sized to this)

// ---------------- ws layout (in 4-byte units) ----------------
#define OFS_ROWPTR 0           // 100001 ints
#define OFS_CNT    100016      // 100000 ints
#define OFS_CURSOR 200032      // 100000 ints
#define OFS_BSUMS  300048      // 128 ints
#define OFS_BOFFS  300176      // 128 ints
#define OFS_STATS  300304      // 3*128 floats (sum[64],sumsq[64] per layer)
#define OFS_CSR    300800      // 1000000 ints
#define OFS_HA     1300800     // 6400000 floats
#define OFS_HB     7700800     // 6400000 floats
#define OFS_XLOC   14100800    // 6400000 floats
#define OFS_PART   20500800    // 2048*128 floats = 262144
// total = 20,762,944 * 4 B ~= 83 MB

// ---------------- d_out layout (floats) ----------------
#define OUT_PRED   0
#define OUT_COMMIT (NN * D)                       // 6,400,000
#define OUT_IDS    (NN * D + 1)                   // 6,400,001
#define OUT_GNN    (NN * D + 1 + NN * (L * RVQ))  // 7,300,001

static __device__ __forceinline__ float waveSum(float v) {
    #pragma unroll
    for (int off = 32; off; off >>= 1) v += __shfl_xor(v, off, 64);
    return v;
}

// ---------------- CSR build ----------------
__global__ void k_count(const int* __restrict__ dst, int* __restrict__ cnt) {
    int e = blockIdx.x * blockDim.x + threadIdx.x;
    if (e < NE) atomicAdd(&cnt[dst[e]], 1);
}

#define SCAN_B 1024
__global__ void k_scan1(const int* __restrict__ cnt, int* __restrict__ rowptr,
                        int* __restrict__ bsums) {
    __shared__ int sm[SCAN_B];
    int t = threadIdx.x;
    int i = blockIdx.x * SCAN_B + t;
    int v = (i < NN) ? cnt[i] : 0;
    sm[t] = v;
    __syncthreads();
    for (int off = 1; off < SCAN_B; off <<= 1) {
        int add = (t >= off) ? sm[t - off] : 0;
        __syncthreads();
        sm[t] += add;
        __syncthreads();
    }
    if (i < NN) rowptr[i + 1] = sm[t];
    if (t == SCAN_B - 1) bsums[blockIdx.x] = sm[t];
}

__global__ void k_scan2(const int* __restrict__ bsums, int* __restrict__ boffs, int nb) {
    __shared__ int sm[SCAN_B];
    int t = threadIdx.x;
    int orig = (t < nb) ? bsums[t] : 0;
    sm[t] = orig;
    __syncthreads();
    for (int off = 1; off < SCAN_B; off <<= 1) {
        int add = (t >= off) ? sm[t - off] : 0;
        __syncthreads();
        sm[t] += add;
        __syncthreads();
    }
    if (t < nb) boffs[t] = sm[t] - orig;  // exclusive
}

__global__ void k_scan3(int* __restrict__ rowptr, const int* __restrict__ boffs) {
    int i = blockIdx.x * SCAN_B + threadIdx.x;
    if (i < NN) rowptr[i + 1] += boffs[blockIdx.x];
    if (i == 0) rowptr[0] = 0;
}

__global__ void k_cursor(const int* __restrict__ rowptr, int* __restrict__ cursor) {
    int i = blockIdx.x * blockDim.x + threadIdx.x;
    if (i < NN) cursor[i] = rowptr[i];
}

__global__ void k_fill(const int* __restrict__ src, const int* __restrict__ dst,
                       int* __restrict__ cursor, int* __restrict__ csr_src) {
    int e = blockIdx.x * blockDim.x + threadIdx.x;
    if (e < NE) {
        int p = atomicAdd(&cursor[dst[e]], 1);
        csr_src[p] = src[e];
    }
}

// Canonicalize row order (insertion sort per row) so that the neighbor-sum
// order — and hence every downstream float — is a deterministic function of
// the edge list, bit-identical across graph replays.
__global__ void k_sortrows(const int* __restrict__ rowptr, int* __restrict__ csr) {
    int n = blockIdx.x * blockDim.x + threadIdx.x;
    if (n >= NN) return;
    int r0 = rowptr[n], r1 = rowptr[n + 1];
    for (int i = r0 + 1; i < r1; ++i) {
        int v = csr[i];
        int j = i - 1;
        while (j >= r0 && csr[j] > v) { csr[j + 1] = csr[j]; --j; }
        csr[j + 1] = v;
    }
}

// ---------------- Layer part A: SAGE conv + skip linear + BN stat partials ----------------
__global__ __launch_bounds__(256) void k_layer_a(
    const float* __restrict__ h, const int* __restrict__ rowptr,
    const int* __restrict__ csr_src,
    const float* __restrict__ Wa, const float* __restrict__ ba,
    const float* __restrict__ Wr, const float* __restrict__ Wl,
    const float* __restrict__ bl,
    float* __restrict__ hp, float* __restrict__ partials) {
    __shared__ float sWa[D * D], sWr[D * D], sWl[D * D];
    __shared__ float sba[D], sbl[D];
    __shared__ float red[2][4][D];
    int t = threadIdx.x;
    for (int i = t; i < D * D; i += 256) {
        sWa[i] = Wa[i];
        sWr[i] = Wr[i];
        sWl[i] = Wl[i];
    }
    if (t < D) { sba[t] = ba[t]; sbl[t] = bl[t]; }
    __syncthreads();

    int lane = t & 63, wid = t >> 6;
    int wg = blockIdx.x * 4 + wid;
    int wstep = gridDim.x * 4;
    float accS = 0.f, accQ = 0.f;

    for (int n = wg; n < NN; n += wstep) {
        int r0 = rowptr[n], r1 = rowptr[n + 1];
        float s = 0.f;
        for (int j = r0; j < r1; ++j) {
            int sidx = csr_src[j];
            s += h[sidx * D + lane];
        }
        float deg = (float)(r1 - r0);
        float mean = s / fmaxf(deg, 1.0f);
        float hv = h[n * D + lane];
        float a = 0.f, r = 0.f, lv = 0.f;
        #pragma unroll 8
        for (int k = 0; k < D; ++k) {
            float mk = __shfl(mean, k, 64);
            float hk = __shfl(hv, k, 64);
            a  += mk * sWa[k * D + lane];
            r  += hk * sWr[k * D + lane];
            lv += hk * sWl[k * D + lane];
        }
        float sage = a + sba[lane] + r;
        float ss = waveSum(sage * sage);
        float inv = 1.0f / (sqrtf(ss) + 1e-12f);
        float hpv = sage * inv + lv + sbl[lane];
        hp[n * D + lane] = hpv;
        accS += hpv;
        accQ += hpv * hpv;
    }

    red[0][wid][lane] = accS;
    red[1][wid][lane] = accQ;
    __syncthreads();
    if (wid == 0) {
        // fixed combine order -> deterministic per-block partial
        float s0 = (red[0][0][lane] + red[0][1][lane]) + (red[0][2][lane] + red[0][3][lane]);
        float q0 = (red[1][0][lane] + red[1][1][lane]) + (red[1][2][lane] + red[1][3][lane]);
        partials[blockIdx.x * 128 + lane]      = s0;
        partials[blockIdx.x * 128 + 64 + lane] = q0;
    }
}

// Deterministic fixed-order reduction of BN stat partials (no atomics).
__global__ void k_red_stats(const float* __restrict__ part, float* __restrict__ stats) {
    int t = threadIdx.x;  // 0..127
    float s0 = 0.f, s1 = 0.f, s2 = 0.f, s3 = 0.f;
    for (int b = 0; b < GRID_A; b += 4) {
        s0 += part[(b + 0) * 128 + t];
        s1 += part[(b + 1) * 128 + t];
        s2 += part[(b + 2) * 128 + t];
        s3 += part[(b + 3) * 128 + t];
    }
    stats[t] = (s0 + s1) + (s2 + s3);
}

// ---------------- Layer part B: BN + ReLU + x_local accumulate + residual VQ ----------------
#define CBSTRIDE 65
__global__ __launch_bounds__(256) void k_layer_b(
    float* __restrict__ hp,              // in: pre-BN h'; out: post-ReLU h
    const float* __restrict__ stats,
    const float* __restrict__ gamma, const float* __restrict__ beta,
    const float* __restrict__ cbs,       // [RVQ][CODES][D] for this layer
    float* __restrict__ x_local,
    float* __restrict__ ids_out,         // [NN][L*RVQ] region base
    int layer, float* __restrict__ commit, int first_layer) {
    __shared__ float scb[RVQ * CODES * CBSTRIDE];
    __shared__ float sscale[D], sshift[D];
    __shared__ float sred[4];
    int t = threadIdx.x, lane = t & 63, wid = t >> 6;

    // normalize codebook rows into LDS (stride 65 to break bank conflicts)
    for (int row = wid; row < RVQ * CODES; row += 4) {
        float v = cbs[row * D + lane];
        float ss = waveSum(v * v);
        scb[row * CBSTRIDE + lane] = v / (sqrtf(ss) + 1e-12f);
    }
    if (t < D) {
        float mu = stats[t] * (1.0f / NN);
        float var = stats[64 + t] * (1.0f / NN) - mu * mu;
        float sc = rsqrtf(var + BN_EPS) * gamma[t];
        sscale[t] = sc;
        sshift[t] = beta[t] - mu * sc;
    }
    __syncthreads();

    float scale = sscale[lane], shift = sshift[lane];
    float closs = 0.f;
    int jj = lane & 15, qq = lane >> 4;
    int wg = blockIdx.x * 4 + wid;
    int wstep = gridDim.x * 4;

    for (int n = wg; n < NN; n += wstep) {
        float hpv = hp[n * D + lane];
        float hn = fmaxf(hpv * scale + shift, 0.f);
        hp[n * D + lane] = hn;
        if (first_layer) x_local[n * D + lane] = hn;
        else x_local[n * D + lane] += hn;

        float res = hn;
        #pragma unroll
        for (int r = 0; r < RVQ; ++r) {
            const float* cb = &scb[r * CODES * CBSTRIDE];
            float p = 0.f;
            #pragma unroll
            for (int tt = 0; tt < 16; ++tt) {
                int c = qq * 16 + tt;
                float rv = __shfl(res, c, 64);
                p += rv * cb[jj * CBSTRIDE + c];
            }
            // combine the 4 quarter-partials (lanes with same jj)
            p += __shfl_xor(p, 16, 64);
            p += __shfl_xor(p, 32, 64);
            // argmax over the 16 codes (replicated across quarters)
            float bv = p;
            int bi = jj;
            #pragma unroll
            for (int off = 8; off; off >>= 1) {
                float ov = __shfl_xor(bv, off, 64);
                int oi = __shfl_xor(bi, off, 64);
                if (ov > bv || (ov == bv && oi < bi)) { bv = ov; bi = oi; }
            }
            float q = cb[bi * CBSTRIDE + lane];
            float d = q - res;
            closs += d * d;
            res -= q;
            if (lane == 0) ids_out[n * (L * RVQ) + layer * RVQ + r] = (float)bi;
        }
    }

    closs = waveSum(closs);
    if (lane == 0) sred[wid] = closs;
    __syncthreads();
    if (t == 0) {
        float tot = (sred[0] + sred[1]) + (sred[2] + sred[3]);
        atomicAdd(commit, tot * (COMMIT_W / (float)(NN * D)));
    }
}

// ---------------- Heads ----------------
__global__ __launch_bounds__(256) void k_head(
    const float* __restrict__ x_local,
    const float* __restrict__ Wp, const float* __restrict__ bp,
    const float* __restrict__ Wg, const float* __restrict__ bg,
    float* __restrict__ pred, float* __restrict__ gnn) {
    __shared__ float sWp[D * D];
    __shared__ float sWg[D * 9];
    __shared__ float sbp[D], sbg[9];
    int t = threadIdx.x;
    for (int i = t; i < D * D; i += 256) sWp[i] = Wp[i];
    for (int i = t; i < D * 9; i += 256) sWg[i] = Wg[i];
    if (t < D) sbp[t] = bp[t];
    if (t < 9) sbg[t] = bg[t];
    __syncthreads();

    int lane = t & 63, wid = t >> 6;
    int wg = blockIdx.x * 4 + wid;
    int wstep = gridDim.x * 4;
    int jsafe = (lane < 9) ? lane : 0;
    for (int n = wg; n < NN; n += wstep) {
        float x = x_local[n * D + lane];
        float p = 0.f, g = 0.f;
        #pragma unroll 8
        for (int k = 0; k < D; ++k) {
            float xk = __shfl(x, k, 64);
            p += xk * sWp[k * D + lane];
            g += xk * sWg[k * 9 + jsafe];
        }
        pred[n * D + lane] = p + sbp[lane];
        if (lane < 9) gnn[n * 9 + lane] = g + sbg[lane];
    }
}

extern "C" void kernel_launch(void* const* d_in, const int* in_sizes, int n_in,
                              void* d_out, int out_size, void* d_ws, size_t ws_size,
                              hipStream_t stream) {
    const float* x   = (const float*)d_in[0];
    const int* ei    = (const int*)d_in[1];
    const float* Wa  = (const float*)d_in[2];
    const float* ba  = (const float*)d_in[3];
    const float* Wr  = (const float*)d_in[4];
    const float* Wl  = (const float*)d_in[5];
    const float* bl  = (const float*)d_in[6];
    const float* gamma = (const float*)d_in[7];
    const float* beta  = (const float*)d_in[8];
    const float* cbs = (const float*)d_in[9];
    const float* Wp  = (const float*)d_in[10];
    const float* bp  = (const float*)d_in[11];
    const float* Wg  = (const float*)d_in[12];
    const float* bg  = (const float*)d_in[13];

    const int* src = ei;
    const int* dst = ei + NE;

    int*   ws_i  = (int*)d_ws;
    float* ws_f  = (float*)d_ws;
    int* rowptr  = ws_i + OFS_ROWPTR;
    int* cnt     = ws_i + OFS_CNT;
    int* cursor  = ws_i + OFS_CURSOR;
    int* bsums   = ws_i + OFS_BSUMS;
    int* boffs   = ws_i + OFS_BOFFS;
    float* stats = ws_f + OFS_STATS;
    int* csr_src = ws_i + OFS_CSR;
    float* hA    = ws_f + OFS_HA;
    float* hB    = ws_f + OFS_HB;
    float* xloc  = ws_f + OFS_XLOC;
    float* part  = ws_f + OFS_PART;

    float* out    = (float*)d_out;
    float* pred   = out + OUT_PRED;
    float* commit = out + OUT_COMMIT;
    float* ids    = out + OUT_IDS;
    float* gnn    = out + OUT_GNN;

    // zero what we accumulate into
    hipMemsetAsync(cnt, 0, NN * sizeof(int), stream);
    hipMemsetAsync(commit, 0, sizeof(float), stream);

    // CSR build
    k_count<<<(NE + 255) / 256, 256, 0, stream>>>(dst, cnt);
    int nscan = (NN + SCAN_B - 1) / SCAN_B;  // 98
    k_scan1<<<nscan, SCAN_B, 0, stream>>>(cnt, rowptr, bsums);
    k_scan2<<<1, SCAN_B, 0, stream>>>(bsums, boffs, nscan);
    k_scan3<<<nscan, SCAN_B, 0, stream>>>(rowptr, boffs);
    k_cursor<<<(NN + 1023) / 1024, 1024, 0, stream>>>(rowptr, cursor);
    k_fill<<<(NE + 255) / 256, 256, 0, stream>>>(src, dst, cursor, csr_src);
    k_sortrows<<<(NN + 255) / 256, 256, 0, stream>>>(rowptr, csr_src);

    // layers
    const float* hin = x;
    float* bufs[2] = {hA, hB};
    for (int i = 0; i < L; ++i) {
        float* hp = bufs[i & 1];
        k_layer_a<<<GRID_A, 256, 0, stream>>>(hin, rowptr, csr_src,
                                              Wa + i * D * D, ba + i * D,
                                              Wr + i * D * D, Wl + i * D * D, bl + i * D,
                                              hp, part);
        k_red_stats<<<1, 128, 0, stream>>>(part, stats + i * 128);
        k_layer_b<<<GRID_A, 256, 0, stream>>>(hp, stats + i * 128,
                                              gamma + i * D, beta + i * D,
                                              cbs + i * RVQ * CODES * D,
                                              xloc, ids, i, commit, (i == 0) ? 1 : 0);
        hin = hp;
    }

    // heads
    k_head<<<2048, 256, 0, stream>>>(xloc, Wp, bp, Wg, bg, pred, gnn);
}

// Round 3
// 1527.128 us; speedup vs baseline: 1.1392x; 1.1392x over previous
//
#include <hip/hip_runtime.h>
#include <math.h>

#define NN 100000
#define NE 1000000
#define D 64
#define L 3
#define RVQ 3
#define CODES 16
#define BN_EPS 1e-5f
#define COMMIT_W 0.25f

#define GRID_A 2048   // blocks for matvec/layer_b kernels (fixed: partials sized to this)

// ---------------- ws layout (in 4-byte units) ----------------
#define OFS_ROWPTR 0           // 100001 ints
#define OFS_CNT    100016      // 100000 ints
#define OFS_CURSOR 200032      // 100000 ints
#define OFS_BSUMS  300048      // 128 ints
#define OFS_BOFFS  300176      // 128 ints
#define OFS_STATS  300304      // 3*128 floats (sum[64],sumsq[64] per layer)
#define OFS_CSR    300800      // 1000000 ints
#define OFS_HA     1300800     // 6400000 floats
#define OFS_HB     7700800     // 6400000 floats
#define OFS_XLOC   14100800    // 6400000 floats
#define OFS_PART   20500800    // 2048*128 floats = 262144
// total = 20,762,944 * 4 B ~= 83 MB

// ---------------- d_out layout (floats) ----------------
#define OUT_PRED   0
#define OUT_COMMIT (NN * D)                       // 6,400,000
#define OUT_IDS    (NN * D + 1)                   // 6,400,001
#define OUT_GNN    (NN * D + 1 + NN * (L * RVQ))  // 7,300,001

static __device__ __forceinline__ float waveSum(float v) {
    #pragma unroll
    for (int off = 32; off; off >>= 1) v += __shfl_xor(v, off, 64);
    return v;
}

// ---------------- CSR build ----------------
__global__ void k_count(const int* __restrict__ dst, int* __restrict__ cnt) {
    int e = blockIdx.x * blockDim.x + threadIdx.x;
    if (e < NE) atomicAdd(&cnt[dst[e]], 1);
}

#define SCAN_B 1024
__global__ void k_scan1(const int* __restrict__ cnt, int* __restrict__ rowptr,
                        int* __restrict__ bsums) {
    __shared__ int sm[SCAN_B];
    int t = threadIdx.x;
    int i = blockIdx.x * SCAN_B + t;
    int v = (i < NN) ? cnt[i] : 0;
    sm[t] = v;
    __syncthreads();
    for (int off = 1; off < SCAN_B; off <<= 1) {
        int add = (t >= off) ? sm[t - off] : 0;
        __syncthreads();
        sm[t] += add;
        __syncthreads();
    }
    if (i < NN) rowptr[i + 1] = sm[t];
    if (t == SCAN_B - 1) bsums[blockIdx.x] = sm[t];
}

__global__ void k_scan2(const int* __restrict__ bsums, int* __restrict__ boffs, int nb) {
    __shared__ int sm[SCAN_B];
    int t = threadIdx.x;
    int orig = (t < nb) ? bsums[t] : 0;
    sm[t] = orig;
    __syncthreads();
    for (int off = 1; off < SCAN_B; off <<= 1) {
        int add = (t >= off) ? sm[t - off] : 0;
        __syncthreads();
        sm[t] += add;
        __syncthreads();
    }
    if (t < nb) boffs[t] = sm[t] - orig;  // exclusive
}

__global__ void k_scan3(int* __restrict__ rowptr, const int* __restrict__ boffs) {
    int i = blockIdx.x * SCAN_B + threadIdx.x;
    if (i < NN) rowptr[i + 1] += boffs[blockIdx.x];
    if (i == 0) rowptr[0] = 0;
}

__global__ void k_cursor(const int* __restrict__ rowptr, int* __restrict__ cursor) {
    int i = blockIdx.x * blockDim.x + threadIdx.x;
    if (i < NN) cursor[i] = rowptr[i];
}

__global__ void k_fill(const int* __restrict__ src, const int* __restrict__ dst,
                       int* __restrict__ cursor, int* __restrict__ csr_src) {
    int e = blockIdx.x * blockDim.x + threadIdx.x;
    if (e < NE) {
        int p = atomicAdd(&cursor[dst[e]], 1);
        csr_src[p] = src[e];
    }
}

// Canonicalize row order so the neighbor-sum order is deterministic.
__global__ void k_sortrows(const int* __restrict__ rowptr, int* __restrict__ csr) {
    int n = blockIdx.x * blockDim.x + threadIdx.x;
    if (n >= NN) return;
    int r0 = rowptr[n], r1 = rowptr[n + 1];
    for (int i = r0 + 1; i < r1; ++i) {
        int v = csr[i];
        int j = i - 1;
        while (j >= r0 && csr[j] > v) { csr[j + 1] = csr[j]; --j; }
        csr[j + 1] = v;
    }
}

// ---------------- Gather: mean of neighbor rows -> mean_out ----------------
// One wave per node; no LDS (max occupancy); lane-cooperative index load +
// 8/4-deep unrolled row loads for memory-level parallelism. Neighbor sum is
// strictly sequential over the sorted row -> bit-identical to the fused R2
// version.
__global__ __launch_bounds__(256) void k_gather(
    const float* __restrict__ h, const int* __restrict__ rowptr,
    const int* __restrict__ csr_src, float* __restrict__ mean_out) {
    int t = threadIdx.x;
    int lane = t & 63, wid = t >> 6;
    int n = blockIdx.x * 4 + wid;
    if (n >= NN) return;

    int r0 = rowptr[n], r1 = rowptr[n + 1];
    float s = 0.f;
    for (int base = r0; base < r1; base += 64) {
        int last = r1 - 1;
        int ii = base + lane;
        int idx = csr_src[(ii <= last) ? ii : last];  // coalesced, clamped
        int m = r1 - base;
        if (m > 64) m = 64;
        int j = 0;
        for (; j + 8 <= m; j += 8) {
            int i0 = __shfl(idx, j + 0, 64), i1 = __shfl(idx, j + 1, 64);
            int i2 = __shfl(idx, j + 2, 64), i3 = __shfl(idx, j + 3, 64);
            int i4 = __shfl(idx, j + 4, 64), i5 = __shfl(idx, j + 5, 64);
            int i6 = __shfl(idx, j + 6, 64), i7 = __shfl(idx, j + 7, 64);
            float v0 = h[i0 * D + lane], v1 = h[i1 * D + lane];
            float v2 = h[i2 * D + lane], v3 = h[i3 * D + lane];
            float v4 = h[i4 * D + lane], v5 = h[i5 * D + lane];
            float v6 = h[i6 * D + lane], v7 = h[i7 * D + lane];
            s += v0; s += v1; s += v2; s += v3;
            s += v4; s += v5; s += v6; s += v7;
        }
        for (; j + 4 <= m; j += 4) {
            int i0 = __shfl(idx, j + 0, 64), i1 = __shfl(idx, j + 1, 64);
            int i2 = __shfl(idx, j + 2, 64), i3 = __shfl(idx, j + 3, 64);
            float v0 = h[i0 * D + lane], v1 = h[i1 * D + lane];
            float v2 = h[i2 * D + lane], v3 = h[i3 * D + lane];
            s += v0; s += v1; s += v2; s += v3;
        }
        for (; j < m; ++j) {
            int i0 = __shfl(idx, j, 64);
            s += h[i0 * D + lane];
        }
    }
    float deg = (float)(r1 - r0);
    mean_out[n * D + lane] = s / fmaxf(deg, 1.0f);
}

// ---------------- Matvec: SAGE transform + skip linear + BN stat partials --
// Reads mean in place from hp (written by k_gather), overwrites hp with h'.
__global__ __launch_bounds__(256) void k_matvec(
    const float* __restrict__ h, float* __restrict__ hp,
    const float* __restrict__ Wa, const float* __restrict__ ba,
    const float* __restrict__ Wr, const float* __restrict__ Wl,
    const float* __restrict__ bl, float* __restrict__ partials) {
    __shared__ float sWa[D * D], sWr[D * D], sWl[D * D];
    __shared__ float sba[D], sbl[D];
    __shared__ float red[2][4][D];
    int t = threadIdx.x;
    for (int i = t; i < D * D; i += 256) {
        sWa[i] = Wa[i];
        sWr[i] = Wr[i];
        sWl[i] = Wl[i];
    }
    if (t < D) { sba[t] = ba[t]; sbl[t] = bl[t]; }
    __syncthreads();

    int lane = t & 63, wid = t >> 6;
    int wg = blockIdx.x * 4 + wid;
    int wstep = gridDim.x * 4;
    float accS = 0.f, accQ = 0.f;

    for (int n = wg; n < NN; n += wstep) {
        float mean = hp[n * D + lane];
        float hv = h[n * D + lane];
        float a = 0.f, r = 0.f, lv = 0.f;
        #pragma unroll 8
        for (int k = 0; k < D; ++k) {
            float mk = __shfl(mean, k, 64);
            float hk = __shfl(hv, k, 64);
            a  += mk * sWa[k * D + lane];
            r  += hk * sWr[k * D + lane];
            lv += hk * sWl[k * D + lane];
        }
        float sage = a + sba[lane] + r;
        float ss = waveSum(sage * sage);
        float inv = 1.0f / (sqrtf(ss) + 1e-12f);
        float hpv = sage * inv + lv + sbl[lane];
        hp[n * D + lane] = hpv;
        accS += hpv;
        accQ += hpv * hpv;
    }

    red[0][wid][lane] = accS;
    red[1][wid][lane] = accQ;
    __syncthreads();
    if (wid == 0) {
        float s0 = (red[0][0][lane] + red[0][1][lane]) + (red[0][2][lane] + red[0][3][lane]);
        float q0 = (red[1][0][lane] + red[1][1][lane]) + (red[1][2][lane] + red[1][3][lane]);
        partials[blockIdx.x * 128 + lane]      = s0;
        partials[blockIdx.x * 128 + 64 + lane] = q0;
    }
}

// Deterministic fixed-order reduction of BN stat partials (no atomics).
__global__ void k_red_stats(const float* __restrict__ part, float* __restrict__ stats) {
    int t = threadIdx.x;  // 0..127
    float s0 = 0.f, s1 = 0.f, s2 = 0.f, s3 = 0.f;
    for (int b = 0; b < GRID_A; b += 4) {
        s0 += part[(b + 0) * 128 + t];
        s1 += part[(b + 1) * 128 + t];
        s2 += part[(b + 2) * 128 + t];
        s3 += part[(b + 3) * 128 + t];
    }
    stats[t] = (s0 + s1) + (s2 + s3);
}

// ---------------- Layer part B: BN + ReLU + x_local accumulate + residual VQ
#define CBSTRIDE 65
__global__ __launch_bounds__(256) void k_layer_b(
    float* __restrict__ hp,              // in: pre-BN h'; out: post-ReLU h
    const float* __restrict__ stats,
    const float* __restrict__ gamma, const float* __restrict__ beta,
    const float* __restrict__ cbs,       // [RVQ][CODES][D] for this layer
    float* __restrict__ x_local,
    float* __restrict__ ids_out,         // [NN][L*RVQ] region base
    int layer, float* __restrict__ commit, int first_layer) {
    __shared__ float scb[RVQ * CODES * CBSTRIDE];
    __shared__ float sscale[D], sshift[D];
    __shared__ float sred[4];
    int t = threadIdx.x, lane = t & 63, wid = t >> 6;

    for (int row = wid; row < RVQ * CODES; row += 4) {
        float v = cbs[row * D + lane];
        float ss = waveSum(v * v);
        scb[row * CBSTRIDE + lane] = v / (sqrtf(ss) + 1e-12f);
    }
    if (t < D) {
        float mu = stats[t] * (1.0f / NN);
        float var = stats[64 + t] * (1.0f / NN) - mu * mu;
        float sc = rsqrtf(var + BN_EPS) * gamma[t];
        sscale[t] = sc;
        sshift[t] = beta[t] - mu * sc;
    }
    __syncthreads();

    float scale = sscale[lane], shift = sshift[lane];
    float closs = 0.f;
    int jj = lane & 15, qq = lane >> 4;
    int wg = blockIdx.x * 4 + wid;
    int wstep = gridDim.x * 4;

    for (int n = wg; n < NN; n += wstep) {
        float hpv = hp[n * D + lane];
        float hn = fmaxf(hpv * scale + shift, 0.f);
        hp[n * D + lane] = hn;
        if (first_layer) x_local[n * D + lane] = hn;
        else x_local[n * D + lane] += hn;

        float res = hn;
        #pragma unroll
        for (int r = 0; r < RVQ; ++r) {
            const float* cb = &scb[r * CODES * CBSTRIDE];
            float p = 0.f;
            #pragma unroll
            for (int tt = 0; tt < 16; ++tt) {
                int c = qq * 16 + tt;
                float rv = __shfl(res, c, 64);
                p += rv * cb[jj * CBSTRIDE + c];
            }
            p += __shfl_xor(p, 16, 64);
            p += __shfl_xor(p, 32, 64);
            float bv = p;
            int bi = jj;
            #pragma unroll
            for (int off = 8; off; off >>= 1) {
                float ov = __shfl_xor(bv, off, 64);
                int oi = __shfl_xor(bi, off, 64);
                if (ov > bv || (ov == bv && oi < bi)) { bv = ov; bi = oi; }
            }
            float q = cb[bi * CBSTRIDE + lane];
            float d = q - res;
            closs += d * d;
            res -= q;
            if (lane == 0) ids_out[n * (L * RVQ) + layer * RVQ + r] = (float)bi;
        }
    }

    closs = waveSum(closs);
    if (lane == 0) sred[wid] = closs;
    __syncthreads();
    if (t == 0) {
        float tot = (sred[0] + sred[1]) + (sred[2] + sred[3]);
        atomicAdd(commit, tot * (COMMIT_W / (float)(NN * D)));
    }
}

// ---------------- Heads ----------------
__global__ __launch_bounds__(256) void k_head(
    const float* __restrict__ x_local,
    const float* __restrict__ Wp, const float* __restrict__ bp,
    const float* __restrict__ Wg, const float* __restrict__ bg,
    float* __restrict__ pred, float* __restrict__ gnn) {
    __shared__ float sWp[D * D];
    __shared__ float sWg[D * 9];
    __shared__ float sbp[D], sbg[9];
    int t = threadIdx.x;
    for (int i = t; i < D * D; i += 256) sWp[i] = Wp[i];
    for (int i = t; i < D * 9; i += 256) sWg[i] = Wg[i];
    if (t < D) sbp[t] = bp[t];
    if (t < 9) sbg[t] = bg[t];
    __syncthreads();

    int lane = t & 63, wid = t >> 6;
    int wg = blockIdx.x * 4 + wid;
    int wstep = gridDim.x * 4;
    int jsafe = (lane < 9) ? lane : 0;
    for (int n = wg; n < NN; n += wstep) {
        float x = x_local[n * D + lane];
        float p = 0.f, g = 0.f;
        #pragma unroll 8
        for (int k = 0; k < D; ++k) {
            float xk = __shfl(x, k, 64);
            p += xk * sWp[k * D + lane];
            g += xk * sWg[k * 9 + jsafe];
        }
        pred[n * D + lane] = p + sbp[lane];
        if (lane < 9) gnn[n * 9 + lane] = g + sbg[lane];
    }
}

extern "C" void kernel_launch(void* const* d_in, const int* in_sizes, int n_in,
                              void* d_out, int out_size, void* d_ws, size_t ws_size,
                              hipStream_t stream) {
    const float* x   = (const float*)d_in[0];
    const int* ei    = (const int*)d_in[1];
    const float* Wa  = (const float*)d_in[2];
    const float* ba  = (const float*)d_in[3];
    const float* Wr  = (const float*)d_in[4];
    const float* Wl  = (const float*)d_in[5];
    const float* bl  = (const float*)d_in[6];
    const float* gamma = (const float*)d_in[7];
    const float* beta  = (const float*)d_in[8];
    const float* cbs = (const float*)d_in[9];
    const float* Wp  = (const float*)d_in[10];
    const float* bp  = (const float*)d_in[11];
    const float* Wg  = (const float*)d_in[12];
    const float* bg  = (const float*)d_in[13];

    const int* src = ei;
    const int* dst = ei + NE;

    int*   ws_i  = (int*)d_ws;
    float* ws_f  = (float*)d_ws;
    int* rowptr  = ws_i + OFS_ROWPTR;
    int* cnt     = ws_i + OFS_CNT;
    int* cursor  = ws_i + OFS_CURSOR;
    int* bsums   = ws_i + OFS_BSUMS;
    int* boffs   = ws_i + OFS_BOFFS;
    float* stats = ws_f + OFS_STATS;
    int* csr_src = ws_i + OFS_CSR;
    float* hA    = ws_f + OFS_HA;
    float* hB    = ws_f + OFS_HB;
    float* xloc  = ws_f + OFS_XLOC;
    float* part  = ws_f + OFS_PART;

    float* out    = (float*)d_out;
    float* pred   = out + OUT_PRED;
    float* commit = out + OUT_COMMIT;
    float* ids    = out + OUT_IDS;
    float* gnn    = out + OUT_GNN;

    hipMemsetAsync(cnt, 0, NN * sizeof(int), stream);
    hipMemsetAsync(commit, 0, sizeof(float), stream);

    // CSR build
    k_count<<<(NE + 255) / 256, 256, 0, stream>>>(dst, cnt);
    int nscan = (NN + SCAN_B - 1) / SCAN_B;  // 98
    k_scan1<<<nscan, SCAN_B, 0, stream>>>(cnt, rowptr, bsums);
    k_scan2<<<1, SCAN_B, 0, stream>>>(bsums, boffs, nscan);
    k_scan3<<<nscan, SCAN_B, 0, stream>>>(rowptr, boffs);
    k_cursor<<<(NN + 1023) / 1024, 1024, 0, stream>>>(rowptr, cursor);
    k_fill<<<(NE + 255) / 256, 256, 0, stream>>>(src, dst, cursor, csr_src);
    k_sortrows<<<(NN + 255) / 256, 256, 0, stream>>>(rowptr, csr_src);

    // layers
    const float* hin = x;
    float* bufs[2] = {hA, hB};
    for (int i = 0; i < L; ++i) {
        float* hp = bufs[i & 1];
        k_gather<<<(NN + 3) / 4, 256, 0, stream>>>(hin, rowptr, csr_src, hp);
        k_matvec<<<GRID_A, 256, 0, stream>>>(hin, hp,
                                             Wa + i * D * D, ba + i * D,
                                             Wr + i * D * D, Wl + i * D * D, bl + i * D,
                                             part);
        k_red_stats<<<1, 128, 0, stream>>>(part, stats + i * 128);
        k_layer_b<<<GRID_A, 256, 0, stream>>>(hp, stats + i * 128,
                                              gamma + i * D, beta + i * D,
                                              cbs + i * RVQ * CODES * D,
                                              xloc, ids, i, commit, (i == 0) ? 1 : 0);
        hin = hp;
    }

    // heads
    k_head<<<2048, 256, 0, stream>>>(xloc, Wp, bp, Wg, bg, pred, gnn);
}

// Round 4
// 1057.567 us; speedup vs baseline: 1.6450x; 1.4440x over previous
//
#include <hip/hip_runtime.h>
#include <math.h>

#define NN 100000
#define NE 1000000
#define D 64
#define L 3
#define RVQ 3
#define CODES 16
#define BN_EPS 1e-5f
#define COMMIT_W 0.25f

#define GRID_A 2048   // blocks for matvec/layer_b kernels (fixed: partials + node mapping)

// ---------------- ws layout (in 4-byte units) ----------------
#define OFS_ROWPTR 0           // 100001 ints
#define OFS_CNT    100016      // 100000 ints
#define OFS_CURSOR 200032      // 100000 ints
#define OFS_BSUMS  300048      // 128 ints
#define OFS_BOFFS  300176      // 128 ints
#define OFS_STATS  300304      // 3*128 floats (sum[64],sumsq[64] per layer)
#define OFS_CSR    300800      // 1000000 ints
#define OFS_HA     1300800     // 6400000 floats
#define OFS_HB     7700800     // 6400000 floats
#define OFS_XLOC   14100800    // 6400000 floats
#define OFS_PART   20500800    // 2048*128 floats = 262144
// total = 20,762,944 * 4 B ~= 83 MB

// ---------------- d_out layout (floats) ----------------
#define OUT_PRED   0
#define OUT_COMMIT (NN * D)                       // 6,400,000
#define OUT_IDS    (NN * D + 1)                   // 6,400,001
#define OUT_GNN    (NN * D + 1 + NN * (L * RVQ))  // 7,300,001

static __device__ __forceinline__ float waveSum(float v) {
    #pragma unroll
    for (int off = 32; off; off >>= 1) v += __shfl_xor(v, off, 64);
    return v;
}

// ---------------- CSR build ----------------
__global__ void k_count(const int* __restrict__ dst, int* __restrict__ cnt) {
    int e = blockIdx.x * blockDim.x + threadIdx.x;
    if (e < NE) atomicAdd(&cnt[dst[e]], 1);
}

#define SCAN_B 1024
__global__ void k_scan1(const int* __restrict__ cnt, int* __restrict__ rowptr,
                        int* __restrict__ bsums) {
    __shared__ int sm[SCAN_B];
    int t = threadIdx.x;
    int i = blockIdx.x * SCAN_B + t;
    int v = (i < NN) ? cnt[i] : 0;
    sm[t] = v;
    __syncthreads();
    for (int off = 1; off < SCAN_B; off <<= 1) {
        int add = (t >= off) ? sm[t - off] : 0;
        __syncthreads();
        sm[t] += add;
        __syncthreads();
    }
    if (i < NN) rowptr[i + 1] = sm[t];
    if (t == SCAN_B - 1) bsums[blockIdx.x] = sm[t];
}

__global__ void k_scan2(const int* __restrict__ bsums, int* __restrict__ boffs, int nb) {
    __shared__ int sm[SCAN_B];
    int t = threadIdx.x;
    int orig = (t < nb) ? bsums[t] : 0;
    sm[t] = orig;
    __syncthreads();
    for (int off = 1; off < SCAN_B; off <<= 1) {
        int add = (t >= off) ? sm[t - off] : 0;
        __syncthreads();
        sm[t] += add;
        __syncthreads();
    }
    if (t < nb) boffs[t] = sm[t] - orig;  // exclusive
}

__global__ void k_scan3(int* __restrict__ rowptr, const int* __restrict__ boffs) {
    int i = blockIdx.x * SCAN_B + threadIdx.x;
    if (i < NN) rowptr[i + 1] += boffs[blockIdx.x];
    if (i == 0) rowptr[0] = 0;
}

__global__ void k_cursor(const int* __restrict__ rowptr, int* __restrict__ cursor) {
    int i = blockIdx.x * blockDim.x + threadIdx.x;
    if (i < NN) cursor[i] = rowptr[i];
}

__global__ void k_fill(const int* __restrict__ src, const int* __restrict__ dst,
                       int* __restrict__ cursor, int* __restrict__ csr_src) {
    int e = blockIdx.x * blockDim.x + threadIdx.x;
    if (e < NE) {
        int p = atomicAdd(&cursor[dst[e]], 1);
        csr_src[p] = src[e];
    }
}

// Canonicalize row order so the neighbor-sum order is deterministic.
__global__ void k_sortrows(const int* __restrict__ rowptr, int* __restrict__ csr) {
    int n = blockIdx.x * blockDim.x + threadIdx.x;
    if (n >= NN) return;
    int r0 = rowptr[n], r1 = rowptr[n + 1];
    for (int i = r0 + 1; i < r1; ++i) {
        int v = csr[i];
        int j = i - 1;
        while (j >= r0 && csr[j] > v) { csr[j + 1] = csr[j]; --j; }
        csr[j + 1] = v;
    }
}

// ---------------- Gather: mean of neighbor rows -> mean_out ----------------
__global__ __launch_bounds__(256) void k_gather(
    const float* __restrict__ h, const int* __restrict__ rowptr,
    const int* __restrict__ csr_src, float* __restrict__ mean_out) {
    int t = threadIdx.x;
    int lane = t & 63, wid = t >> 6;
    int n = blockIdx.x * 4 + wid;
    if (n >= NN) return;

    int r0 = rowptr[n], r1 = rowptr[n + 1];
    float s = 0.f;
    for (int base = r0; base < r1; base += 64) {
        int last = r1 - 1;
        int ii = base + lane;
        int idx = csr_src[(ii <= last) ? ii : last];  // coalesced, clamped
        int m = r1 - base;
        if (m > 64) m = 64;
        int j = 0;
        for (; j + 8 <= m; j += 8) {
            int i0 = __shfl(idx, j + 0, 64), i1 = __shfl(idx, j + 1, 64);
            int i2 = __shfl(idx, j + 2, 64), i3 = __shfl(idx, j + 3, 64);
            int i4 = __shfl(idx, j + 4, 64), i5 = __shfl(idx, j + 5, 64);
            int i6 = __shfl(idx, j + 6, 64), i7 = __shfl(idx, j + 7, 64);
            float v0 = h[i0 * D + lane], v1 = h[i1 * D + lane];
            float v2 = h[i2 * D + lane], v3 = h[i3 * D + lane];
            float v4 = h[i4 * D + lane], v5 = h[i5 * D + lane];
            float v6 = h[i6 * D + lane], v7 = h[i7 * D + lane];
            s += v0; s += v1; s += v2; s += v3;
            s += v4; s += v5; s += v6; s += v7;
        }
        for (; j + 4 <= m; j += 4) {
            int i0 = __shfl(idx, j + 0, 64), i1 = __shfl(idx, j + 1, 64);
            int i2 = __shfl(idx, j + 2, 64), i3 = __shfl(idx, j + 3, 64);
            float v0 = h[i0 * D + lane], v1 = h[i1 * D + lane];
            float v2 = h[i2 * D + lane], v3 = h[i3 * D + lane];
            s += v0; s += v1; s += v2; s += v3;
        }
        for (; j < m; ++j) {
            int i0 = __shfl(idx, j, 64);
            s += h[i0 * D + lane];
        }
    }
    float deg = (float)(r1 - r0);
    mean_out[n * D + lane] = s / fmaxf(deg, 1.0f);
}

// ---------------- Matvec: SAGE transform + skip linear + BN stat partials --
// lane = output channel. Weights register-resident (192 VGPRs/wave, loaded
// once). Activation rows are wave-uniform -> readfirstlane forces scalar
// broadcast loads; zero LDS-pipe ops in the k-loop. Accumulation order per
// output is k-ascending, identical to the previous version (bit-identical).
__global__ __launch_bounds__(256, 2) void k_matvec(
    const float* __restrict__ h, float* __restrict__ hp,
    const float* __restrict__ Wa, const float* __restrict__ ba,
    const float* __restrict__ Wr, const float* __restrict__ Wl,
    const float* __restrict__ bl, float* __restrict__ partials) {
    __shared__ float red[2][4][D];
    int t = threadIdx.x, lane = t & 63, wid = t >> 6;

    float wa[D], wr[D], wl[D];
    #pragma unroll
    for (int k = 0; k < D; ++k) {
        wa[k] = Wa[k * D + lane];
        wr[k] = Wr[k * D + lane];
        wl[k] = Wl[k * D + lane];
    }
    float bav = ba[lane], blv = bl[lane];

    int wg = blockIdx.x * 4 + wid;
    int wstep = gridDim.x * 4;
    float accS = 0.f, accQ = 0.f;

    for (int n = wg; n < NN; n += wstep) {
        int nu = __builtin_amdgcn_readfirstlane(n);
        const float4* mrow = (const float4*)(hp + (size_t)nu * D);
        const float4* hrow = (const float4*)(h + (size_t)nu * D);
        float a = 0.f, r = 0.f, lv = 0.f;
        #pragma unroll
        for (int j = 0; j < 16; ++j) {
            float4 m4 = mrow[j];
            float4 h4 = hrow[j];
            a += m4.x * wa[4 * j + 0]; r += h4.x * wr[4 * j + 0]; lv += h4.x * wl[4 * j + 0];
            a += m4.y * wa[4 * j + 1]; r += h4.y * wr[4 * j + 1]; lv += h4.y * wl[4 * j + 1];
            a += m4.z * wa[4 * j + 2]; r += h4.z * wr[4 * j + 2]; lv += h4.z * wl[4 * j + 2];
            a += m4.w * wa[4 * j + 3]; r += h4.w * wr[4 * j + 3]; lv += h4.w * wl[4 * j + 3];
        }
        float sage = a + bav + r;
        float ss = waveSum(sage * sage);
        float inv = 1.0f / (sqrtf(ss) + 1e-12f);
        float hpv = sage * inv + lv + blv;
        hp[(size_t)n * D + lane] = hpv;
        accS += hpv;
        accQ += hpv * hpv;
    }

    red[0][wid][lane] = accS;
    red[1][wid][lane] = accQ;
    __syncthreads();
    if (wid == 0) {
        float s0 = (red[0][0][lane] + red[0][1][lane]) + (red[0][2][lane] + red[0][3][lane]);
        float q0 = (red[1][0][lane] + red[1][1][lane]) + (red[1][2][lane] + red[1][3][lane]);
        partials[blockIdx.x * 128 + lane]      = s0;
        partials[blockIdx.x * 128 + 64 + lane] = q0;
    }
}

// Deterministic fixed-order reduction of BN stat partials (no atomics).
__global__ void k_red_stats(const float* __restrict__ part, float* __restrict__ stats) {
    int t = threadIdx.x;  // 0..127
    float s0 = 0.f, s1 = 0.f, s2 = 0.f, s3 = 0.f;
    for (int b = 0; b < GRID_A; b += 4) {
        s0 += part[(b + 0) * 128 + t];
        s1 += part[(b + 1) * 128 + t];
        s2 += part[(b + 2) * 128 + t];
        s3 += part[(b + 3) * 128 + t];
    }
    stats[t] = (s0 + s1) + (s2 + s3);
}

// ---------------- Layer part B: BN + ReLU + x_local accumulate + residual VQ
// Codebook fragment register-resident (48 VGPRs); residual staged in LDS once
// per level and read back as 4x ds_read_b128 (replaces 16 bpermutes + 16 LDS
// reads). All float expressions and orders identical to previous version.
#define CBSTRIDE 65
__global__ __launch_bounds__(256) void k_layer_b(
    float* __restrict__ hp,              // in: pre-BN h'; out: post-ReLU h
    const float* __restrict__ stats,
    const float* __restrict__ gamma, const float* __restrict__ beta,
    const float* __restrict__ cbs,       // [RVQ][CODES][D] for this layer
    float* __restrict__ x_local,
    float* __restrict__ ids_out,         // [NN][L*RVQ] region base
    int layer, float* __restrict__ commit, int first_layer) {
    __shared__ float scb[RVQ * CODES * CBSTRIDE];
    __shared__ float sres[256];
    __shared__ float sred[4];
    int t = threadIdx.x, lane = t & 63, wid = t >> 6;

    // normalize codebook rows into LDS (identical math to before)
    for (int row = wid; row < RVQ * CODES; row += 4) {
        float v = cbs[row * D + lane];
        float ss = waveSum(v * v);
        scb[row * CBSTRIDE + lane] = v / (sqrtf(ss) + 1e-12f);
    }
    __syncthreads();

    int jj = lane & 15, qq = lane >> 4;
    // per-lane codebook fragment: cbr[r][tt] = cbn[r][jj][qq*16+tt]
    float cbr[RVQ][16];
    #pragma unroll
    for (int r = 0; r < RVQ; ++r)
        #pragma unroll
        for (int tt = 0; tt < 16; ++tt)
            cbr[r][tt] = scb[(r * CODES + jj) * CBSTRIDE + qq * 16 + tt];

    float mu = stats[lane] * (1.0f / NN);
    float var = stats[64 + lane] * (1.0f / NN) - mu * mu;
    float scale = rsqrtf(var + BN_EPS) * gamma[lane];
    float shift = beta[lane] - mu * scale;

    float closs = 0.f;
    int wg = blockIdx.x * 4 + wid;
    int wstep = gridDim.x * 4;

    for (int n = wg; n < NN; n += wstep) {
        float hpv = hp[n * D + lane];
        float hn = fmaxf(hpv * scale + shift, 0.f);
        hp[n * D + lane] = hn;
        if (first_layer) x_local[n * D + lane] = hn;
        else x_local[n * D + lane] += hn;

        float res = hn;
        int bis[RVQ];
        #pragma unroll
        for (int r = 0; r < RVQ; ++r) {
            sres[t] = res;                       // wave-private slot, no barrier
            float rc[16];
            #pragma unroll
            for (int i = 0; i < 4; ++i) {
                float4 v4 = *((const float4*)&sres[wid * 64 + qq * 16 + 4 * i]);
                rc[4 * i + 0] = v4.x; rc[4 * i + 1] = v4.y;
                rc[4 * i + 2] = v4.z; rc[4 * i + 3] = v4.w;
            }
            float p = 0.f;
            #pragma unroll
            for (int tt = 0; tt < 16; ++tt) p += rc[tt] * cbr[r][tt];
            p += __shfl_xor(p, 16, 64);
            p += __shfl_xor(p, 32, 64);
            float bv = p;
            int bi = jj;
            #pragma unroll
            for (int off = 8; off; off >>= 1) {
                float ov = __shfl_xor(bv, off, 64);
                int oi = __shfl_xor(bi, off, 64);
                if (ov > bv || (ov == bv && oi < bi)) { bv = ov; bi = oi; }
            }
            float q = scb[(r * CODES + bi) * CBSTRIDE + lane];
            float d = q - res;
            closs += d * d;
            res -= q;
            bis[r] = bi;
        }
        if (lane == 0) {
            ids_out[n * (L * RVQ) + layer * RVQ + 0] = (float)bis[0];
            ids_out[n * (L * RVQ) + layer * RVQ + 1] = (float)bis[1];
            ids_out[n * (L * RVQ) + layer * RVQ + 2] = (float)bis[2];
        }
    }

    closs = waveSum(closs);
    if (lane == 0) sred[wid] = closs;
    __syncthreads();
    if (t == 0) {
        float tot = (sred[0] + sred[1]) + (sred[2] + sred[3]);
        atomicAdd(commit, tot * (COMMIT_W / (float)(NN * D)));
    }
}

// ---------------- Heads ----------------
__global__ __launch_bounds__(256, 2) void k_head(
    const float* __restrict__ x_local,
    const float* __restrict__ Wp, const float* __restrict__ bp,
    const float* __restrict__ Wg, const float* __restrict__ bg,
    float* __restrict__ pred, float* __restrict__ gnn) {
    int t = threadIdx.x, lane = t & 63, wid = t >> 6;
    int jsafe = (lane < 9) ? lane : 0;

    float wp[D], wg[D];
    #pragma unroll
    for (int k = 0; k < D; ++k) {
        wp[k] = Wp[k * D + lane];
        wg[k] = Wg[k * 9 + jsafe];
    }
    float bpv = bp[lane], bgv = bg[jsafe];

    int w = blockIdx.x * 4 + wid;
    int wstep = gridDim.x * 4;
    for (int n = w; n < NN; n += wstep) {
        int nu = __builtin_amdgcn_readfirstlane(n);
        const float4* xrow = (const float4*)(x_local + (size_t)nu * D);
        float p = 0.f, g = 0.f;
        #pragma unroll
        for (int j = 0; j < 16; ++j) {
            float4 x4 = xrow[j];
            p += x4.x * wp[4 * j + 0]; g += x4.x * wg[4 * j + 0];
            p += x4.y * wp[4 * j + 1]; g += x4.y * wg[4 * j + 1];
            p += x4.z * wp[4 * j + 2]; g += x4.z * wg[4 * j + 2];
            p += x4.w * wp[4 * j + 3]; g += x4.w * wg[4 * j + 3];
        }
        pred[(size_t)n * D + lane] = p + bpv;
        if (lane < 9) gnn[(size_t)n * 9 + lane] = g + bgv;
    }
}

extern "C" void kernel_launch(void* const* d_in, const int* in_sizes, int n_in,
                              void* d_out, int out_size, void* d_ws, size_t ws_size,
                              hipStream_t stream) {
    const float* x   = (const float*)d_in[0];
    const int* ei    = (const int*)d_in[1];
    const float* Wa  = (const float*)d_in[2];
    const float* ba  = (const float*)d_in[3];
    const float* Wr  = (const float*)d_in[4];
    const float* Wl  = (const float*)d_in[5];
    const float* bl  = (const float*)d_in[6];
    const float* gamma = (const float*)d_in[7];
    const float* beta  = (const float*)d_in[8];
    const float* cbs = (const float*)d_in[9];
    const float* Wp  = (const float*)d_in[10];
    const float* bp  = (const float*)d_in[11];
    const float* Wg  = (const float*)d_in[12];
    const float* bg  = (const float*)d_in[13];

    const int* src = ei;
    const int* dst = ei + NE;

    int*   ws_i  = (int*)d_ws;
    float* ws_f  = (float*)d_ws;
    int* rowptr  = ws_i + OFS_ROWPTR;
    int* cnt     = ws_i + OFS_CNT;
    int* cursor  = ws_i + OFS_CURSOR;
    int* bsums   = ws_i + OFS_BSUMS;
    int* boffs   = ws_i + OFS_BOFFS;
    float* stats = ws_f + OFS_STATS;
    int* csr_src = ws_i + OFS_CSR;
    float* hA    = ws_f + OFS_HA;
    float* hB    = ws_f + OFS_HB;
    float* xloc  = ws_f + OFS_XLOC;
    float* part  = ws_f + OFS_PART;

    float* out    = (float*)d_out;
    float* pred   = out + OUT_PRED;
    float* commit = out + OUT_COMMIT;
    float* ids    = out + OUT_IDS;
    float* gnn    = out + OUT_GNN;

    hipMemsetAsync(cnt, 0, NN * sizeof(int), stream);
    hipMemsetAsync(commit, 0, sizeof(float), stream);

    // CSR build
    k_count<<<(NE + 255) / 256, 256, 0, stream>>>(dst, cnt);
    int nscan = (NN + SCAN_B - 1) / SCAN_B;  // 98
    k_scan1<<<nscan, SCAN_B, 0, stream>>>(cnt, rowptr, bsums);
    k_scan2<<<1, SCAN_B, 0, stream>>>(bsums, boffs, nscan);
    k_scan3<<<nscan, SCAN_B, 0, stream>>>(rowptr, boffs);
    k_cursor<<<(NN + 1023) / 1024, 1024, 0, stream>>>(rowptr, cursor);
    k_fill<<<(NE + 255) / 256, 256, 0, stream>>>(src, dst, cursor, csr_src);
    k_sortrows<<<(NN + 255) / 256, 256, 0, stream>>>(rowptr, csr_src);

    // layers
    const float* hin = x;
    float* bufs[2] = {hA, hB};
    for (int i = 0; i < L; ++i) {
        float* hp = bufs[i & 1];
        k_gather<<<(NN + 3) / 4, 256, 0, stream>>>(hin, rowptr, csr_src, hp);
        k_matvec<<<GRID_A, 256, 0, stream>>>(hin, hp,
                                             Wa + i * D * D, ba + i * D,
                                             Wr + i * D * D, Wl + i * D * D, bl + i * D,
                                             part);
        k_red_stats<<<1, 128, 0, stream>>>(part, stats + i * 128);
        k_layer_b<<<GRID_A, 256, 0, stream>>>(hp, stats + i * 128,
                                              gamma + i * D, beta + i * D,
                                              cbs + i * RVQ * CODES * D,
                                              xloc, ids, i, commit, (i == 0) ? 1 : 0);
        hin = hp;
    }

    // heads
    k_head<<<2048, 256, 0, stream>>>(xloc, Wp, bp, Wg, bg, pred, gnn);
}